// Round 8
// baseline (111.397 us; speedup 1.0000x reference)
//
#include <hip/hip_runtime.h>

// LogisticRegressionRBF: out[k] = sigmoid( sum_n w[n]*exp(-||x_k - c_n||^2) + b )
// K=65536, N=4096, M=64. fp32 in/out.
//
// R8: 512-thread blocks (512 blocks = 2/CU, 16 waves/CU same as R7) --
// halves L2 traffic for cb (every block reads all 512 KB of cb; 1024->512
// readers). Wave = rowgrp(2) x colgrp(4): 64 rows x 32-center slice; per-wave
// profile identical to R7. Plus:
//   - depth-2 register prefetch (2 sets, LOADT(c+2) after compute(c))
//   - 2 underflow branches/chunk (max over all 4 rg per tt) vs R7's 4
//   - p4v via __shfl (no LDS x2s, no preamble barrier)
// Watchdogs: WRITE_SIZE ~256 KB (no spills), VGPR <= 128 (16 waves/CU).

#define KOBS 65536
#define NCENT 4096
#define MFEAT 64
#define BR 128                      // x-rows per block (8 waves)
#define BN 128                      // centers per chunk
#define NCHUNK (NCENT / BN)         // 32
#define KBLK (KOBS / BR)            // 512

#define SCALE_A 2.8853900817779268f   // 2*log2(e)
#define QS      1.4426950408889634f   // log2(e)
#define TSKIP   -60.0f

typedef __attribute__((ext_vector_type(8))) short short8;
typedef __attribute__((ext_vector_type(4))) float float4v;
typedef __attribute__((ext_vector_type(2))) float float2v;

#if __has_builtin(__builtin_amdgcn_exp2f)
#define EXP2F(x) __builtin_amdgcn_exp2f(x)
#else
#define EXP2F(x) exp2f(x)
#endif

static __device__ inline short f2bf(float f) {
    unsigned int u = __float_as_uint(f);
    unsigned int r = (u + 0x7fffu + ((u >> 16) & 1u)) >> 16;
    return (short)r;
}

// Fused prep. Blocks [0,128): octet transpose xb fp32 -> cb bf16 in MFMA
// fragment order. Blocks [128,1152): hc2w[n] = { -log2e*||c_n||^2, w[n] }.
__global__ __launch_bounds__(256) void rbf_prep(
    const float* __restrict__ xb, const float* __restrict__ w,
    short* __restrict__ cb, float2v* __restrict__ hc2w) {
    const int bid = blockIdx.x;
    const int tid = threadIdx.x;
    if (bid < 128) {
        const int o    = bid * 256 + tid;        // octet index, [0, 32768)
        const int tile = o >> 7;
        const int r    = o & 127;
        const int p    = r >> 6;
        const int g    = (r >> 4) & 3;
        const int mm   = r & 15;
        const int row  = tile * 16 + mm;
        const int k0   = p * 32 + g * 8;
        float4v v0 = *(const float4v*)(xb + row * MFEAT + k0);
        float4v v1 = *(const float4v*)(xb + row * MFEAT + k0 + 4);
        short8 oct;
        #pragma unroll
        for (int j = 0; j < 4; ++j) { oct[j] = f2bf(v0[j]); oct[j + 4] = f2bf(v1[j]); }
        *(short8*)(cb + o * 8) = oct;
    } else {
        const int row  = (bid - 128) * 4 + (tid >> 6);
        const int lane = tid & 63;
        float v = xb[row * MFEAT + lane];
        float s = v * v;
        #pragma unroll
        for (int off = 32; off > 0; off >>= 1) s += __shfl_xor(s, off, 64);
        if (lane == 0) {
            float2v hw = {-QS * s, w[row]};
            hc2w[row] = hw;
        }
    }
}

__global__ __launch_bounds__(512, 4) void rbf_main(
    const float* __restrict__ x, const short* __restrict__ cb,
    const float2v* __restrict__ hc2w, const float* __restrict__ bptr,
    float* __restrict__ out) {
    __shared__ float red[4][BR];    // [colgrp][block row], 2 KB

    const int tid    = threadIdx.x;
    const int wave   = tid >> 6;
    const int lane   = tid & 63;
    const int m      = lane & 15;
    const int g      = lane >> 4;
    const int rowgrp = wave >> 2;           // 0..1 -> which 64 rows
    const int colgrp = wave & 3;            // 0..3 -> which 32-center slice
    const int r0w    = (int)blockIdx.x * BR + rowgrp * 64;

    // ---- A fragments for this wave's 64 rows, scaled by 2*log2e ----
    short8 af[4][2];
    float  ssr[4];
    #pragma unroll
    for (int rg = 0; rg < 4; ++rg) {
        const float* xr = x + (r0w + rg * 16 + m) * MFEAT + g * 8;
        float4v a0 = *(const float4v*)(xr);
        float4v a1 = *(const float4v*)(xr + 4);
        float4v a2 = *(const float4v*)(xr + 32);
        float4v a3 = *(const float4v*)(xr + 36);
        float ss = 0.0f;
        #pragma unroll
        for (int i = 0; i < 4; ++i) {
            af[rg][0][i]     = f2bf(SCALE_A * a0[i]);  ss = fmaf(a0[i], a0[i], ss);
            af[rg][0][i + 4] = f2bf(SCALE_A * a1[i]);  ss = fmaf(a1[i], a1[i], ss);
            af[rg][1][i]     = f2bf(SCALE_A * a2[i]);  ss = fmaf(a2[i], a2[i], ss);
            af[rg][1][i + 4] = f2bf(SCALE_A * a3[i]);  ss = fmaf(a3[i], a3[i], ss);
        }
        ss += __shfl_xor(ss, 16, 64);
        ss += __shfl_xor(ss, 32, 64);
        ssr[rg] = ss;    // all lanes with same m hold row (rg*16+m)'s sum
    }

    // C-init tuples via cross-lane pull (no LDS, no barrier):
    // p4v[rg][i] = -log2e * x2[row rg*16 + g*4 + i]; source lane g*4+i holds it.
    float4v p4v[4];
    #pragma unroll
    for (int rg = 0; rg < 4; ++rg)
        #pragma unroll
        for (int i = 0; i < 4; ++i)
            p4v[rg][i] = -QS * __shfl(ssr[rg], g * 4 + i, 64);

    float accw[4][4];
    #pragma unroll
    for (int rg = 0; rg < 4; ++rg)
        #pragma unroll
        for (int i = 0; i < 4; ++i) accw[rg][i] = 0.0f;

    // ---- B fragment base: colgrp picks tiles {2*colgrp, 2*colgrp+1} ----
    const char* cbb = (const char*)cb + colgrp * 4096 + lane * 16;
    const float2v* hwp = hc2w + colgrp * 32 + m;

    // depth-2 ping-pong prefetch: B frags + {tq = TSKIP - q, w}
    short8  pb0[2][2], pb1[2][2];
    float2v phw[2][2];

    #define LOADT(c, s) do {                                                   \
        _Pragma("unroll")                                                      \
        for (int tt = 0; tt < 2; ++tt) {                                       \
            pb0[s][tt] = *(const short8*)(cbb + (c) * 16384 + tt * 2048);      \
            pb1[s][tt] = *(const short8*)(cbb + (c) * 16384 + tt * 2048 + 1024);\
            float2v hw_ = hwp[(c) * 128 + tt * 16];                            \
            hw_.x = TSKIP - hw_.x;                                             \
            phw[s][tt] = hw_;                                                  \
        }                                                                      \
    } while (0)

    LOADT(0, 0);
    LOADT(1, 1);

    #pragma unroll 2
    for (int c = 0; c < NCHUNK; ++c) {
        const int cur = c & 1;
        #pragma unroll
        for (int tt = 0; tt < 2; ++tt) {
            short8 b0 = pb0[cur][tt];
            short8 b1 = pb1[cur][tt];
            float  tq = phw[cur][tt].x;
            float  wv = phw[cur][tt].y;
            float4v a[4];
            #pragma unroll
            for (int rg = 0; rg < 4; ++rg) {
                a[rg] = __builtin_amdgcn_mfma_f32_16x16x32_bf16(
                    af[rg][0], b0, p4v[rg], 0, 0, 0);     // acc = dot + p
                a[rg] = __builtin_amdgcn_mfma_f32_16x16x32_bf16(
                    af[rg][1], b1, a[rg], 0, 0, 0);
            }
            float mx = -3.0e38f;
            #pragma unroll
            for (int rg = 0; rg < 4; ++rg)
                mx = fmaxf(mx, fmaxf(fmaxf(a[rg][0], a[rg][1]),
                                     fmaxf(a[rg][2], a[rg][3])));
            if (__any(mx > tq)) {                 // rare (~1e-4 of groups)
                float q = TSKIP - tq;
                #pragma unroll
                for (int rg = 0; rg < 4; ++rg)
                    #pragma unroll
                    for (int i = 0; i < 4; ++i)
                        accw[rg][i] = fmaf(wv, EXP2F(a[rg][i] + q), accw[rg][i]);
            }
        }
        if (c + 2 < NCHUNK) LOADT(c + 2, cur);    // refill the set just consumed
    }

    // ---- reduce over 16 n-lanes; combine 4 colgrps via LDS; sigmoid ----
    #pragma unroll
    for (int rg = 0; rg < 4; ++rg)
        #pragma unroll
        for (int i = 0; i < 4; ++i) {
            float v = accw[rg][i];
            v += __shfl_xor(v, 1, 64);
            v += __shfl_xor(v, 2, 64);
            v += __shfl_xor(v, 4, 64);
            v += __shfl_xor(v, 8, 64);
            accw[rg][i] = v;
        }
    if (m == 0) {   // lanes 0,16,32,48: g = 0..3
        #pragma unroll
        for (int rg = 0; rg < 4; ++rg)
            #pragma unroll
            for (int i = 0; i < 4; ++i)
                red[colgrp][rowgrp * 64 + rg * 16 + g * 4 + i] = accw[rg][i];
    }
    __syncthreads();
    if (tid < BR) {
        float z = red[0][tid] + red[1][tid] + red[2][tid] + red[3][tid]
                + bptr[0];
        out[(int)blockIdx.x * BR + tid] = 1.0f / (1.0f + EXP2F(-QS * z));
    }
}

extern "C" void kernel_launch(void* const* d_in, const int* in_sizes, int n_in,
                              void* d_out, int out_size, void* d_ws, size_t ws_size,
                              hipStream_t stream) {
    const float* x  = (const float*)d_in[0];   // [K, M]
    const float* xb = (const float*)d_in[1];   // [N, M]
    const float* w  = (const float*)d_in[2];   // [1, N]
    const float* b  = (const float*)d_in[3];   // [1]
    float* out = (float*)d_out;                // [K]

    short*   cb   = (short*)d_ws;                                 // 512 KB
    float2v* hc2w = (float2v*)((char*)d_ws + NCENT * MFEAT * 2);  // 32 KB

    rbf_prep<<<128 + NCENT / 4, 256, 0, stream>>>(xb, w, cb, hc2w);
    rbf_main<<<KBLK, 512, 0, stream>>>(x, cb, hc2w, b, out);
}